// Round 2
// baseline (469.246 us; speedup 1.0000x reference)
//
#include <hip/hip_runtime.h>

#define NB 4
#define NN 512
#define ND 256
#define NH 256

// Block-wide reduce (256 threads = 4 waves of 64). ismax: max else sum.
__device__ __forceinline__ float blockReduce(float v, float* red, bool ismax) {
#pragma unroll
    for (int o = 32; o > 0; o >>= 1) {
        float t = __shfl_down(v, o);
        v = ismax ? fmaxf(v, t) : (v + t);
    }
    int wid = threadIdx.x >> 6;
    __syncthreads();  // protect red[] from any previous reduction's readers
    if ((threadIdx.x & 63) == 0) red[wid] = v;
    __syncthreads();
    float r = red[0];
#pragma unroll
    for (int w = 1; w < 4; ++w) r = ismax ? fmaxf(r, red[w]) : (r + red[w]);
    return r;
}

// ---------------- K1: q/k/v projections -> fp32 workspace ----------------
// grid (2048, 3): blockIdx.x = b*N+n row, blockIdx.y selects q/k/v
__global__ __launch_bounds__(256) void qkv_kernel(
    const float* __restrict__ x,
    const float* __restrict__ Wq, const float* __restrict__ bq,
    const float* __restrict__ Wk, const float* __restrict__ bk,
    const float* __restrict__ Wv, const float* __restrict__ bv,
    float* __restrict__ q, float* __restrict__ k, float* __restrict__ v)
{
    const int row = blockIdx.x;
    const int which = blockIdx.y;
    const float* W   = (which == 0) ? Wq : (which == 1) ? Wk : Wv;
    const float* bia = (which == 0) ? bq : (which == 1) ? bk : bv;
    float* out       = (which == 0) ? q  : (which == 1) ? k  : v;

    __shared__ float xs[ND];
    const int tid = threadIdx.x;
    xs[tid] = x[row * ND + tid];
    __syncthreads();

    const float4* Wr = (const float4*)(W + tid * ND);  // row `tid` of (H,D) weight
    float acc = bia[tid];
    const float4* xs4 = (const float4*)xs;
#pragma unroll 8
    for (int d4 = 0; d4 < ND / 4; ++d4) {
        float4 w = Wr[d4], xv = xs4[d4];
        acc += xv.x * w.x + xv.y * w.y + xv.z * w.z + xv.w * w.w;
    }
    out[row * NH + tid] = acc;
}

// ---------------- K2: fused attention + edge gate + softmax + PV + LNs ----------------
// one block per (b, i); 256 threads
__global__ __launch_bounds__(256) void fused_kernel(
    const float* __restrict__ x, const float* __restrict__ area, const float* __restrict__ co,
    const float* __restrict__ We1, const float* __restrict__ be1,
    const float* __restrict__ We2, const float* __restrict__ be2,
    const float* __restrict__ Wo, const float* __restrict__ bo,
    const float* __restrict__ g_ot, const float* __restrict__ b_ot,
    const float* __restrict__ g1, const float* __restrict__ b1,
    const float* __restrict__ g2, const float* __restrict__ b2,
    const float* __restrict__ q, const float* __restrict__ k, const float* __restrict__ v,
    float* __restrict__ out)
{
    const int tid = threadIdx.x;
    const int b = blockIdx.x >> 9;
    const int i = blockIdx.x & (NN - 1);

    __shared__ float qs[NH];
    __shared__ float als[NH], w1s[NH], w2s[NH];
    __shared__ float srow[NN];
    __shared__ float y1[NH];
    __shared__ float red[4];

    const float a = area[b * NN + i];
    qs[tid]  = q[(b * NN + i) * NH + tid];
    als[tid] = fmaf(a, We1[2 * tid], be1[tid]);  // a*We1[h,0]+be1[h]
    w1s[tid] = We1[2 * tid + 1];
    w2s[tid] = We2[tid];
    const float be2f = be2[0];
    __syncthreads();

    // scores(i,j)/sqrt(H) * sigmoid(edge MLP)
    for (int j = tid; j < NN; j += 256) {
        const float4* kr = (const float4*)(k + (b * NN + j) * NH);
        float dot = 0.f;
        const float4* qs4 = (const float4*)qs;
#pragma unroll 8
        for (int d4 = 0; d4 < NH / 4; ++d4) {
            float4 kv = kr[d4], qv = qs4[d4];
            dot += qv.x * kv.x + qv.y * kv.y + qv.z * kv.z + qv.w * kv.w;
        }
        const float c = co[i * NN + j];
        float e = 0.f;
        const float4* A4  = (const float4*)als;
        const float4* W14 = (const float4*)w1s;
        const float4* W24 = (const float4*)w2s;
#pragma unroll 8
        for (int h4 = 0; h4 < NH / 4; ++h4) {
            float4 A = A4[h4], W1 = W14[h4], W2 = W24[h4];
            e += fmaxf(fmaf(c, W1.x, A.x), 0.f) * W2.x;
            e += fmaxf(fmaf(c, W1.y, A.y), 0.f) * W2.y;
            e += fmaxf(fmaf(c, W1.z, A.z), 0.f) * W2.z;
            e += fmaxf(fmaf(c, W1.w, A.w), 0.f) * W2.w;
        }
        const float ew = 1.f / (1.f + __expf(-(e + be2f)));
        srow[j] = dot * 0.0625f * ew;  // 1/sqrt(256)
    }
    __syncthreads();

    // softmax over j
    float s0 = srow[tid], s1 = srow[tid + 256];
    float m = blockReduce(fmaxf(s0, s1), red, true);
    float e0 = __expf(s0 - m), e1 = __expf(s1 - m);
    float sum = blockReduce(e0 + e1, red, false);
    float inv = 1.f / sum;
    __syncthreads();
    srow[tid] = e0 * inv;
    srow[tid + 256] = e1 * inv;
    __syncthreads();

    // out_h = sum_j P[j] * v[b,j,h]   (coalesced column reads)
    float acc = 0.f;
    {
        const float* vp = v + (size_t)b * NN * NH + tid;
        for (int j = 0; j < NN; ++j)
            acc = fmaf(srow[j], vp[j * NH], acc);
    }

    // LN1
    float mean = blockReduce(acc, red, false) * (1.f / 256.f);
    float d0 = acc - mean;
    float var = blockReduce(d0 * d0, red, false) * (1.f / 256.f);
    float yv = d0 * rsqrtf(var + 1e-5f) * g1[tid] + b1[tid];
    __syncthreads();
    y1[tid] = yv;
    __syncthreads();

    // out2_o = sum_h y1[h] * Wo[o,h] + bo[o]
    float acc2 = bo[tid];
    const float4* Wr = (const float4*)(Wo + tid * NH);
    const float4* y14 = (const float4*)y1;
#pragma unroll 8
    for (int d4 = 0; d4 < NH / 4; ++d4) {
        float4 w = Wr[d4], yv4 = y14[d4];
        acc2 += yv4.x * w.x + yv4.y * w.y + yv4.z * w.z + yv4.w * w.w;
    }

    // LN(g_ot,b_ot) + relu
    float mean2 = blockReduce(acc2, red, false) * (1.f / 256.f);
    float d2 = acc2 - mean2;
    float var2 = blockReduce(d2 * d2, red, false) * (1.f / 256.f);
    float z = fmaxf(d2 * rsqrtf(var2 + 1e-5f) * g_ot[tid] + b_ot[tid], 0.f);

    // residual + LN2
    float t = z + x[(b * NN + i) * ND + tid];
    float mean3 = blockReduce(t, red, false) * (1.f / 256.f);
    float d3 = t - mean3;
    float var3 = blockReduce(d3 * d3, red, false) * (1.f / 256.f);
    float o = d3 * rsqrtf(var3 + 1e-5f) * g2[tid] + b2[tid];

    out[(b * NN + i) * NH + tid] = o;
}

extern "C" void kernel_launch(void* const* d_in, const int* in_sizes, int n_in,
                              void* d_out, int out_size, void* d_ws, size_t ws_size,
                              hipStream_t stream) {
    const float* x    = (const float*)d_in[0];
    const float* area = (const float*)d_in[1];
    const float* co   = (const float*)d_in[2];
    const float* Wq   = (const float*)d_in[3];
    const float* bq   = (const float*)d_in[4];
    const float* Wk   = (const float*)d_in[5];
    const float* bk   = (const float*)d_in[6];
    const float* Wv   = (const float*)d_in[7];
    const float* bv   = (const float*)d_in[8];
    const float* We1  = (const float*)d_in[9];
    const float* be1  = (const float*)d_in[10];
    const float* We2  = (const float*)d_in[11];
    const float* be2  = (const float*)d_in[12];
    const float* Wo   = (const float*)d_in[13];
    const float* bo   = (const float*)d_in[14];
    const float* g_ot = (const float*)d_in[15];
    const float* b_ot = (const float*)d_in[16];
    const float* g1   = (const float*)d_in[17];
    const float* b1   = (const float*)d_in[18];
    const float* g2   = (const float*)d_in[19];
    const float* b2   = (const float*)d_in[20];

    float* q = (float*)d_ws;
    float* k = q + (size_t)NB * NN * NH;
    float* v = k + (size_t)NB * NN * NH;

    qkv_kernel<<<dim3(NB * NN, 3), 256, 0, stream>>>(x, Wq, bq, Wk, bk, Wv, bv, q, k, v);
    fused_kernel<<<NB * NN, 256, 0, stream>>>(x, area, co, We1, be1, We2, be2, Wo, bo,
                                              g_ot, b_ot, g1, b1, g2, b2, q, k, v,
                                              (float*)d_out);
}

// Round 3
// 275.130 us; speedup vs baseline: 1.7055x; 1.7055x over previous
//
#include <hip/hip_runtime.h>

#define NB 4
#define NN 512
#define ND 256
#define NH 256

// Block-wide reduce (256 threads = 4 waves of 64). ismax: max else sum.
__device__ __forceinline__ float blockReduce(float v, float* red, bool ismax) {
#pragma unroll
    for (int o = 32; o > 0; o >>= 1) {
        float t = __shfl_down(v, o);
        v = ismax ? fmaxf(v, t) : (v + t);
    }
    int wid = threadIdx.x >> 6;
    __syncthreads();
    if ((threadIdx.x & 63) == 0) red[wid] = v;
    __syncthreads();
    float r = red[0];
#pragma unroll
    for (int w = 1; w < 4; ++w) r = ismax ? fmaxf(r, red[w]) : (r + red[w]);
    return r;
}

// ---------------- K1: q/k/v projections as tiled GEMM ----------------
// grid (32 row-tiles, 4 h-tiles, 3 = q/k/v), 256 threads, 4x4 acc/thread.
// q, v written row-major [row][h]; k written TRANSPOSED k_t[b][h][n].
#define BM 64
#define BN 64
#define BK 64
#define TP 68  // padded leading dim (words) for transposed LDS tiles; %4==0 keeps b128 aligned

__global__ __launch_bounds__(256) void qkv_gemm(
    const float* __restrict__ x,
    const float* __restrict__ Wq, const float* __restrict__ bq,
    const float* __restrict__ Wk, const float* __restrict__ bk,
    const float* __restrict__ Wv, const float* __restrict__ bv,
    float* __restrict__ q, float* __restrict__ k_t, float* __restrict__ v)
{
    const int which = blockIdx.z;
    const float* W   = (which == 0) ? Wq : (which == 1) ? Wk : Wv;
    const float* bia = (which == 0) ? bq : (which == 1) ? bk : bv;

    const int row0 = blockIdx.x * BM;
    const int h0   = blockIdx.y * BN;
    const int tid  = threadIdx.x;
    const int tx = tid & 15, ty = tid >> 4;

    __shared__ float xs[BK * TP];  // [d][r] transposed
    __shared__ float ws[BK * TP];  // [d][h] transposed

    float acc[4][4];
#pragma unroll
    for (int r = 0; r < 4; ++r)
#pragma unroll
        for (int c = 0; c < 4; ++c) acc[r][c] = 0.f;

    for (int kc = 0; kc < ND / BK; ++kc) {
        const int d0 = kc * BK;
        // stage x tile and W tile (coalesced float4 reads, transposed LDS writes)
#pragma unroll
        for (int it = 0; it < 4; ++it) {
            int vid = tid + it * 256;       // float4 id 0..1023
            int r  = vid >> 4;              // 0..63 (row or h)
            int c4 = vid & 15;              // 0..15
            float4 xv = *(const float4*)&x[(size_t)(row0 + r) * ND + d0 + c4 * 4];
            xs[(4 * c4 + 0) * TP + r] = xv.x;
            xs[(4 * c4 + 1) * TP + r] = xv.y;
            xs[(4 * c4 + 2) * TP + r] = xv.z;
            xs[(4 * c4 + 3) * TP + r] = xv.w;
            float4 wv = *(const float4*)&W[(size_t)(h0 + r) * ND + d0 + c4 * 4];
            ws[(4 * c4 + 0) * TP + r] = wv.x;
            ws[(4 * c4 + 1) * TP + r] = wv.y;
            ws[(4 * c4 + 2) * TP + r] = wv.z;
            ws[(4 * c4 + 3) * TP + r] = wv.w;
        }
        __syncthreads();
#pragma unroll 8
        for (int d = 0; d < BK; ++d) {
            float4 av = *(const float4*)&xs[d * TP + ty * 4];
            float4 bv4 = *(const float4*)&ws[d * TP + tx * 4];
            acc[0][0] += av.x * bv4.x; acc[0][1] += av.x * bv4.y; acc[0][2] += av.x * bv4.z; acc[0][3] += av.x * bv4.w;
            acc[1][0] += av.y * bv4.x; acc[1][1] += av.y * bv4.y; acc[1][2] += av.y * bv4.z; acc[1][3] += av.y * bv4.w;
            acc[2][0] += av.z * bv4.x; acc[2][1] += av.z * bv4.y; acc[2][2] += av.z * bv4.z; acc[2][3] += av.z * bv4.w;
            acc[3][0] += av.w * bv4.x; acc[3][1] += av.w * bv4.y; acc[3][2] += av.w * bv4.z; acc[3][3] += av.w * bv4.w;
        }
        __syncthreads();
    }

    const float4 bia4 = *(const float4*)&bia[h0 + tx * 4];
    if (which == 1) {
        // k: write transposed k_t[(b*NH + h)*NN + n]
#pragma unroll
        for (int r = 0; r < 4; ++r) {
            int row = row0 + ty * 4 + r;
            int bb = row >> 9, n = row & (NN - 1);
#pragma unroll
            for (int c = 0; c < 4; ++c) {
                int h = h0 + tx * 4 + c;
                float bv2 = (c == 0) ? bia4.x : (c == 1) ? bia4.y : (c == 2) ? bia4.z : bia4.w;
                k_t[((size_t)bb * NH + h) * NN + n] = acc[r][c] + bv2;
            }
        }
    } else {
        float* out = (which == 0) ? q : v;
#pragma unroll
        for (int r = 0; r < 4; ++r) {
            int row = row0 + ty * 4 + r;
            float4 o = make_float4(acc[r][0] + bia4.x, acc[r][1] + bia4.y,
                                   acc[r][2] + bia4.z, acc[r][3] + bia4.w);
            *(float4*)&out[(size_t)row * NH + h0 + tx * 4] = o;
        }
    }
}

// ---------------- K2: fused attention + PWL edge gate + softmax + PV + LNs ----------------
// one block per (b, i); 256 threads
__global__ __launch_bounds__(256) void fused_kernel(
    const float* __restrict__ x, const float* __restrict__ area, const float* __restrict__ co,
    const float* __restrict__ We1, const float* __restrict__ be1,
    const float* __restrict__ We2, const float* __restrict__ be2,
    const float* __restrict__ Wo, const float* __restrict__ bo,
    const float* __restrict__ g_ot, const float* __restrict__ b_ot,
    const float* __restrict__ g1, const float* __restrict__ b1,
    const float* __restrict__ g2, const float* __restrict__ b2,
    const float* __restrict__ q, const float* __restrict__ k_t, const float* __restrict__ v,
    float* __restrict__ out)
{
    const int tid = threadIdx.x;
    const int b = blockIdx.x >> 9;
    const int i = blockIdx.x & (NN - 1);

    __shared__ float qs[NH];
    __shared__ float ts[NH];
    __shared__ int   sidx[NH];
    __shared__ float slo[NH], sib[NH];
    __shared__ float2 sc0[NH], sc1[NH];
    __shared__ float prefS[NH + 1], prefB[NH + 1];
    __shared__ float srow[NN];
    __shared__ float y1[NH];
    __shared__ float red[4];

    const float a = area[b * NN + i];
    qs[tid] = q[(size_t)(b * NN + i) * NH + tid];
    const float be2f = be2[0];

    // ---- edge gate: e(c) = sum_h relu(w1*c + al)*w2 is piecewise-linear in c ----
    {
        float w1 = We1[2 * tid + 1];
        float al = fmaf(a, We1[2 * tid], be1[tid]);
        float w2 = We2[tid];
        float s = w1 * w2, bb = al * w2;
        float baseS = 0.f, baseB = 0.f;
        float t = 3e38f, es = 0.f, eb = 0.f;
        if (w1 == 0.f) {
            if (al > 0.f) baseB = bb;                 // constant term
        } else {
            float tt = -al / w1;
            if (w1 > 0.f) {                           // active iff c > tt
                if (tt <= 0.f)      { baseS = s; baseB = bb; }
                else if (tt < 1.f)  { t = tt; es = s; eb = bb; }
                // tt >= 1: never active (c < 1)
            } else {                                  // active iff c < tt
                if (tt >= 1.f)      { baseS = s; baseB = bb; }
                else if (tt > 0.f)  { t = tt; es = -s; eb = -bb; baseS = s; baseB = bb; }
                // tt <= 0: never active (c >= 0)
            }
        }
        ts[tid] = t; sidx[tid] = tid; slo[tid] = es; sib[tid] = eb;
        baseS = blockReduce(baseS, red, false);
        baseB = blockReduce(baseB, red, false);
        __syncthreads();

        // bitonic sort (ts, sidx) ascending, 256 elements
        for (int k2 = 2; k2 <= 256; k2 <<= 1) {
            for (int jj = k2 >> 1; jj > 0; jj >>= 1) {
                int p = tid ^ jj;
                if (p > tid) {
                    float t0 = ts[tid], t1 = ts[p];
                    bool up = ((tid & k2) == 0);
                    if ((t0 > t1) == up) {
                        ts[tid] = t1; ts[p] = t0;
                        int i0 = sidx[tid]; sidx[tid] = sidx[p]; sidx[p] = i0;
                    }
                }
                __syncthreads();
            }
        }

        // gather deltas in sorted order, inclusive scan (Hillis-Steele, ping-pong)
        int sid = sidx[tid];
        sc0[tid] = make_float2(slo[sid], sib[sid]);
        __syncthreads();
        float2* src = sc0; float2* dst = sc1;
        for (int off = 1; off < 256; off <<= 1) {
            float2 vv = src[tid];
            if (tid >= off) { float2 u = src[tid - off]; vv.x += u.x; vv.y += u.y; }
            dst[tid] = vv;
            __syncthreads();
            float2* tmp = src; src = dst; dst = tmp;
        }
        float2 r2 = src[tid];
        prefS[tid + 1] = baseS + r2.x;
        prefB[tid + 1] = baseB + r2.y;
        if (tid == 0) { prefS[0] = baseS; prefB[0] = baseB; }
        __syncthreads();
    }

    // ---- scores: (q . k_j)/16 * sigmoid(e(c_ij) + be2) for j pair {2t, 2t+1} ----
    {
        const float* kt = k_t + (size_t)b * NH * NN;
        const int j0 = 2 * tid;
        float dot0 = 0.f, dot1 = 0.f;
#pragma unroll 4
        for (int h = 0; h < NH; h += 4) {
            float4 qv = *(const float4*)&qs[h];
            float2 kv;
            kv = *(const float2*)&kt[(size_t)(h + 0) * NN + j0]; dot0 = fmaf(qv.x, kv.x, dot0); dot1 = fmaf(qv.x, kv.y, dot1);
            kv = *(const float2*)&kt[(size_t)(h + 1) * NN + j0]; dot0 = fmaf(qv.y, kv.x, dot0); dot1 = fmaf(qv.y, kv.y, dot1);
            kv = *(const float2*)&kt[(size_t)(h + 2) * NN + j0]; dot0 = fmaf(qv.z, kv.x, dot0); dot1 = fmaf(qv.z, kv.y, dot1);
            kv = *(const float2*)&kt[(size_t)(h + 3) * NN + j0]; dot0 = fmaf(qv.w, kv.x, dot0); dot1 = fmaf(qv.w, kv.y, dot1);
        }
        float2 c2 = *(const float2*)&co[(size_t)i * NN + j0];
        int r0 = 0, r1 = 0;
#pragma unroll
        for (int st = 128; st; st >>= 1) {
            if (ts[r0 + st - 1] <= c2.x) r0 += st;
            if (ts[r1 + st - 1] <= c2.y) r1 += st;
        }
        float e0 = fmaf(c2.x, prefS[r0], prefB[r0]);
        float e1 = fmaf(c2.y, prefS[r1], prefB[r1]);
        float ew0 = 1.f / (1.f + __expf(-(e0 + be2f)));
        float ew1 = 1.f / (1.f + __expf(-(e1 + be2f)));
        srow[j0]     = dot0 * 0.0625f * ew0;
        srow[j0 + 1] = dot1 * 0.0625f * ew1;
    }
    __syncthreads();

    // ---- softmax over j ----
    float s0 = srow[tid], s1 = srow[tid + 256];
    float m = blockReduce(fmaxf(s0, s1), red, true);
    float e0 = __expf(s0 - m), e1 = __expf(s1 - m);
    float sum = blockReduce(e0 + e1, red, false);
    float inv = 1.f / sum;
    __syncthreads();
    srow[tid] = e0 * inv;
    srow[tid + 256] = e1 * inv;
    __syncthreads();

    // ---- out_h = sum_j P[j] * v[b,j,h] (coalesced column reads) ----
    float acc = 0.f;
    {
        const float* vp = v + (size_t)b * NN * NH + tid;
        for (int j = 0; j < NN; ++j)
            acc = fmaf(srow[j], vp[(size_t)j * NH], acc);
    }

    // ---- LN1 ----
    float mean = blockReduce(acc, red, false) * (1.f / 256.f);
    float d0 = acc - mean;
    float var = blockReduce(d0 * d0, red, false) * (1.f / 256.f);
    float yv = d0 * rsqrtf(var + 1e-5f) * g1[tid] + b1[tid];
    __syncthreads();
    y1[tid] = yv;
    __syncthreads();

    // ---- out2_o = sum_h y1[h] * Wo[o,h] + bo[o] ----
    float acc2 = bo[tid];
    const float4* Wr = (const float4*)(Wo + (size_t)tid * NH);
    const float4* y14 = (const float4*)y1;
#pragma unroll 8
    for (int d4 = 0; d4 < NH / 4; ++d4) {
        float4 w = Wr[d4], yv4 = y14[d4];
        acc2 += yv4.x * w.x + yv4.y * w.y + yv4.z * w.z + yv4.w * w.w;
    }

    // ---- LN(g_ot,b_ot) + relu ----
    float mean2 = blockReduce(acc2, red, false) * (1.f / 256.f);
    float d2 = acc2 - mean2;
    float var2 = blockReduce(d2 * d2, red, false) * (1.f / 256.f);
    float z = fmaxf(d2 * rsqrtf(var2 + 1e-5f) * g_ot[tid] + b_ot[tid], 0.f);

    // ---- residual + LN2 ----
    float t = z + x[(size_t)(b * NN + i) * ND + tid];
    float mean3 = blockReduce(t, red, false) * (1.f / 256.f);
    float d3 = t - mean3;
    float var3 = blockReduce(d3 * d3, red, false) * (1.f / 256.f);
    float o = d3 * rsqrtf(var3 + 1e-5f) * g2[tid] + b2[tid];

    out[(size_t)(b * NN + i) * NH + tid] = o;
}

extern "C" void kernel_launch(void* const* d_in, const int* in_sizes, int n_in,
                              void* d_out, int out_size, void* d_ws, size_t ws_size,
                              hipStream_t stream) {
    const float* x    = (const float*)d_in[0];
    const float* area = (const float*)d_in[1];
    const float* co   = (const float*)d_in[2];
    const float* Wq   = (const float*)d_in[3];
    const float* bq   = (const float*)d_in[4];
    const float* Wk   = (const float*)d_in[5];
    const float* bk   = (const float*)d_in[6];
    const float* Wv   = (const float*)d_in[7];
    const float* bv   = (const float*)d_in[8];
    const float* We1  = (const float*)d_in[9];
    const float* be1  = (const float*)d_in[10];
    const float* We2  = (const float*)d_in[11];
    const float* be2  = (const float*)d_in[12];
    const float* Wo   = (const float*)d_in[13];
    const float* bo   = (const float*)d_in[14];
    const float* g_ot = (const float*)d_in[15];
    const float* b_ot = (const float*)d_in[16];
    const float* g1   = (const float*)d_in[17];
    const float* b1   = (const float*)d_in[18];
    const float* g2   = (const float*)d_in[19];
    const float* b2   = (const float*)d_in[20];

    float* q   = (float*)d_ws;
    float* k_t = q + (size_t)NB * NN * NH;
    float* v   = k_t + (size_t)NB * NN * NH;

    qkv_gemm<<<dim3(NB * NN / BM, NH / BN, 3), 256, 0, stream>>>(
        x, Wq, bq, Wk, bk, Wv, bv, q, k_t, v);
    fused_kernel<<<NB * NN, 256, 0, stream>>>(x, area, co, We1, be1, We2, be2, Wo, bo,
                                              g_ot, b_ot, g1, b1, g2, b2, q, k_t, v,
                                              (float*)d_out);
}

// Round 4
// 225.907 us; speedup vs baseline: 2.0772x; 1.2179x over previous
//
#include <hip/hip_runtime.h>

#define NB 4
#define NN 512
#define ND 256
#define NH 256
#define TI 4

// ---- block-wide reduce of 4 independent values (one per i-tile) ----
// 256 threads = 4 waves of 64. Two barriers per call.
__device__ __forceinline__ float4 blockReduce4(float4 v, float4* red4b, bool ismax) {
#pragma unroll
    for (int o = 32; o > 0; o >>= 1) {
        float4 t;
        t.x = __shfl_down(v.x, o); t.y = __shfl_down(v.y, o);
        t.z = __shfl_down(v.z, o); t.w = __shfl_down(v.w, o);
        if (ismax) {
            v.x = fmaxf(v.x, t.x); v.y = fmaxf(v.y, t.y);
            v.z = fmaxf(v.z, t.z); v.w = fmaxf(v.w, t.w);
        } else {
            v.x += t.x; v.y += t.y; v.z += t.z; v.w += t.w;
        }
    }
    int wid = threadIdx.x >> 6;
    __syncthreads();
    if ((threadIdx.x & 63) == 0) red4b[wid] = v;
    __syncthreads();
    float4 r = red4b[0];
#pragma unroll
    for (int w = 1; w < 4; ++w) {
        float4 u = red4b[w];
        if (ismax) {
            r.x = fmaxf(r.x, u.x); r.y = fmaxf(r.y, u.y);
            r.z = fmaxf(r.z, u.z); r.w = fmaxf(r.w, u.w);
        } else {
            r.x += u.x; r.y += u.y; r.z += u.z; r.w += u.w;
        }
    }
    return r;
}

// ---------------- K0: transpose the four 256x256 weight matrices ----------------
__global__ __launch_bounds__(256) void transpose_w(
    const float* __restrict__ Wq, const float* __restrict__ Wk,
    const float* __restrict__ Wv, const float* __restrict__ Wo,
    float* __restrict__ Wqt, float* __restrict__ Wkt,
    float* __restrict__ Wvt, float* __restrict__ Wot)
{
    const int z = blockIdx.z;
    const float* src = (z == 0) ? Wq : (z == 1) ? Wk : (z == 2) ? Wv : Wo;
    float* dst       = (z == 0) ? Wqt : (z == 1) ? Wkt : (z == 2) ? Wvt : Wot;
    __shared__ float t[32][33];
    const int tx = threadIdx.x & 31, ty = threadIdx.x >> 5;  // ty 0..7
#pragma unroll
    for (int k = 0; k < 4; ++k)
        t[ty + 8 * k][tx] = src[(blockIdx.y * 32 + ty + 8 * k) * 256 + blockIdx.x * 32 + tx];
    __syncthreads();
#pragma unroll
    for (int k = 0; k < 4; ++k)
        dst[(blockIdx.x * 32 + ty + 8 * k) * 256 + blockIdx.y * 32 + tx] = t[tx][ty + 8 * k];
}

// ---------------- K1: q/k/v projections, weights pre-transposed ----------------
// grid (128 row-tiles of 16, 3 = q/k/v), 256 threads; thread <-> output h.
// x rows are wave-uniform loads (s_load); W^T reads coalesced.
// q, v row-major; k written transposed k_t[b][h][n] via LDS retranspose.
__global__ __launch_bounds__(256) void qkv_proj(
    const float* __restrict__ x,
    const float* __restrict__ Wqt, const float* __restrict__ bq,
    const float* __restrict__ Wkt, const float* __restrict__ bk,
    const float* __restrict__ Wvt, const float* __restrict__ bv,
    float* __restrict__ q, float* __restrict__ k_t, float* __restrict__ v)
{
    const int which = blockIdx.y;
    const float* Wt  = (which == 0) ? Wqt : (which == 1) ? Wkt : Wvt;
    const float* bia = (which == 0) ? bq : (which == 1) ? bk : bv;
    const int row0 = blockIdx.x * 16;
    const int tid = threadIdx.x;

    float acc[16];
#pragma unroll
    for (int r = 0; r < 16; ++r) acc[r] = 0.f;

    for (int d4 = 0; d4 < 64; ++d4) {
        const int d = 4 * d4;
        float w0 = Wt[(d + 0) * 256 + tid];
        float w1 = Wt[(d + 1) * 256 + tid];
        float w2 = Wt[(d + 2) * 256 + tid];
        float w3 = Wt[(d + 3) * 256 + tid];
#pragma unroll
        for (int r = 0; r < 16; ++r) {
            float4 xv = *(const float4*)&x[(size_t)(row0 + r) * 256 + d];  // uniform -> s_load
            acc[r] += xv.x * w0 + xv.y * w1 + xv.z * w2 + xv.w * w3;
        }
    }

    const float biav = bia[tid];
    __shared__ float tile[16][260];
    if (which != 1) {
        float* out = (which == 0) ? q : v;
#pragma unroll
        for (int r = 0; r < 16; ++r)
            out[(size_t)(row0 + r) * 256 + tid] = acc[r] + biav;
    } else {
        const int b = row0 >> 9, n0 = row0 & (NN - 1);
#pragma unroll
        for (int r = 0; r < 16; ++r) tile[r][tid] = acc[r] + biav;
        __syncthreads();
        const int nq = tid & 15, hq = tid >> 4;
#pragma unroll
        for (int hh = 0; hh < 16; ++hh) {
            int h = hh * 16 + hq;
            k_t[((size_t)b * 256 + h) * 512 + n0 + nq] = tile[nq][h];
        }
    }
}

// ---------------- K2: fused attention, TI=4 query rows per block ----------------
__global__ __launch_bounds__(256) void fused_kernel(
    const float* __restrict__ x, const float* __restrict__ area, const float* __restrict__ co,
    const float* __restrict__ We1, const float* __restrict__ be1,
    const float* __restrict__ We2, const float* __restrict__ be2,
    const float* __restrict__ Wot, const float* __restrict__ bo,
    const float* __restrict__ g_ot, const float* __restrict__ b_ot,
    const float* __restrict__ g1, const float* __restrict__ b1,
    const float* __restrict__ g2, const float* __restrict__ b2,
    const float* __restrict__ q, const float* __restrict__ k_t, const float* __restrict__ v,
    float* __restrict__ out)
{
    const int tid = threadIdx.x;
    const int b = blockIdx.x >> 7;
    const int i0 = (blockIdx.x & 127) << 2;

    __shared__ float qs[TI * 256];   // later reused as y1
    __shared__ float ts[TI * 256];   // breakpoints (sorted in place)
    __shared__ float ea[TI * 256];   // slope deltas (sorted, then inclusive-scanned)
    __shared__ float eb[TI * 256];   // intercept deltas
    __shared__ float srow[TI * 512]; // scores -> probs
    __shared__ float4 red4b[4];

    // stage q rows
#pragma unroll
    for (int ti = 0; ti < TI; ++ti)
        qs[ti * 256 + tid] = q[(size_t)(b * NN + i0 + ti) * NH + tid];

    // ---- gate build: e(c) = sum_h relu(w1*c + al)*w2, PWL in c ----
    const float w10 = We1[2 * tid], w11 = We1[2 * tid + 1];
    const float w2v = We2[tid], be1v = be1[tid];
    const float be2f = be2[0];
    float4 bS4 = make_float4(0, 0, 0, 0), bB4 = make_float4(0, 0, 0, 0);
#pragma unroll
    for (int ti = 0; ti < TI; ++ti) {
        const float a = area[b * NN + i0 + ti];
        float al = fmaf(a, w10, be1v);
        float s = w11 * w2v, bb = al * w2v;
        float t = 3e38f, es = 0.f, ebv = 0.f, baS = 0.f, baB = 0.f;
        if (w11 == 0.f) {
            if (al > 0.f) baB = bb;
        } else {
            float tt = -al / w11;
            if (w11 > 0.f) {
                if (tt <= 0.f)      { baS = s; baB = bb; }
                else if (tt < 1.f)  { t = tt; es = s; ebv = bb; }
            } else {
                if (tt >= 1.f)      { baS = s; baB = bb; }
                else if (tt > 0.f)  { t = tt; es = -s; ebv = -bb; baS = s; baB = bb; }
            }
        }
        ts[ti * 256 + tid] = t; ea[ti * 256 + tid] = es; eb[ti * 256 + tid] = ebv;
        ((float*)&bS4)[ti] = baS; ((float*)&bB4)[ti] = baB;
    }
    const float4 baseS4 = blockReduce4(bS4, red4b, false);
    const float4 baseB4 = blockReduce4(bB4, red4b, false);

    // ---- bitonic sort of the 4 breakpoint sets in parallel (key ts, payload ea/eb) ----
    for (int k2 = 2; k2 <= 256; k2 <<= 1) {
        for (int jj = k2 >> 1; jj > 0; jj >>= 1) {
            __syncthreads();
            int p = tid ^ jj;
            if (p > tid) {
                bool up = ((tid & k2) == 0);
#pragma unroll
                for (int ti = 0; ti < TI; ++ti) {
                    int a0 = ti * 256 + tid, a1 = ti * 256 + p;
                    float t0 = ts[a0], t1 = ts[a1];
                    if ((t0 > t1) == up) {
                        ts[a0] = t1; ts[a1] = t0;
                        float u = ea[a0]; ea[a0] = ea[a1]; ea[a1] = u;
                        u = eb[a0]; eb[a0] = eb[a1]; eb[a1] = u;
                    }
                }
            }
        }
    }
    __syncthreads();

    // ---- inclusive scan of (ea, eb) in place ----
    for (int off = 1; off < 256; off <<= 1) {
        float va[TI], vb[TI];
#pragma unroll
        for (int ti = 0; ti < TI; ++ti) {
            va[ti] = ea[ti * 256 + tid]; vb[ti] = eb[ti * 256 + tid];
            if (tid >= off) { va[ti] += ea[ti * 256 + tid - off]; vb[ti] += eb[ti * 256 + tid - off]; }
        }
        __syncthreads();
#pragma unroll
        for (int ti = 0; ti < TI; ++ti) { ea[ti * 256 + tid] = va[ti]; eb[ti * 256 + tid] = vb[ti]; }
        __syncthreads();
    }

    // ---- scores: (q_i . k_j)/16 * sigmoid(e(c_ij)+be2), j pair {2t,2t+1} ----
    const int j0 = 2 * tid;
    float dA[TI], dB[TI];
#pragma unroll
    for (int ti = 0; ti < TI; ++ti) { dA[ti] = 0.f; dB[ti] = 0.f; }
    {
        const float* kt = k_t + (size_t)b * NH * NN;
        for (int h4 = 0; h4 < 64; ++h4) {
            const int h = 4 * h4;
            float2 ka = *(const float2*)&kt[(size_t)(h + 0) * NN + j0];
            float2 kb = *(const float2*)&kt[(size_t)(h + 1) * NN + j0];
            float2 kc = *(const float2*)&kt[(size_t)(h + 2) * NN + j0];
            float2 kd = *(const float2*)&kt[(size_t)(h + 3) * NN + j0];
#pragma unroll
            for (int ti = 0; ti < TI; ++ti) {
                float4 qv = *(const float4*)&qs[ti * 256 + h];
                dA[ti] += qv.x * ka.x + qv.y * kb.x + qv.z * kc.x + qv.w * kd.x;
                dB[ti] += qv.x * ka.y + qv.y * kb.y + qv.z * kc.y + qv.w * kd.y;
            }
        }
    }
    float sA[TI], sB[TI];
#pragma unroll
    for (int ti = 0; ti < TI; ++ti) {
        float2 c2 = *(const float2*)&co[(size_t)(i0 + ti) * NN + j0];
        int r0 = 0, r1 = 0;
#pragma unroll
        for (int st = 128; st; st >>= 1) {
            if (ts[ti * 256 + r0 + st - 1] <= c2.x) r0 += st;
            if (ts[ti * 256 + r1 + st - 1] <= c2.y) r1 += st;
        }
        float S0 = ((const float*)&baseS4)[ti] + (r0 ? ea[ti * 256 + r0 - 1] : 0.f);
        float B0 = ((const float*)&baseB4)[ti] + (r0 ? eb[ti * 256 + r0 - 1] : 0.f);
        float S1 = ((const float*)&baseS4)[ti] + (r1 ? ea[ti * 256 + r1 - 1] : 0.f);
        float B1 = ((const float*)&baseB4)[ti] + (r1 ? eb[ti * 256 + r1 - 1] : 0.f);
        float e0 = fmaf(c2.x, S0, B0), e1 = fmaf(c2.y, S1, B1);
        float ew0 = 1.f / (1.f + __expf(-(e0 + be2f)));
        float ew1 = 1.f / (1.f + __expf(-(e1 + be2f)));
        sA[ti] = dA[ti] * 0.0625f * ew0;
        sB[ti] = dB[ti] * 0.0625f * ew1;
    }

    // ---- softmax over j (values live in registers) ----
    float4 m4 = make_float4(fmaxf(sA[0], sB[0]), fmaxf(sA[1], sB[1]),
                            fmaxf(sA[2], sB[2]), fmaxf(sA[3], sB[3]));
    m4 = blockReduce4(m4, red4b, true);
    float eA[TI], eB[TI];
    float4 sum4;
#pragma unroll
    for (int ti = 0; ti < TI; ++ti) {
        float m = ((const float*)&m4)[ti];
        eA[ti] = __expf(sA[ti] - m); eB[ti] = __expf(sB[ti] - m);
        ((float*)&sum4)[ti] = eA[ti] + eB[ti];
    }
    sum4 = blockReduce4(sum4, red4b, false);
#pragma unroll
    for (int ti = 0; ti < TI; ++ti) {
        float inv = 1.f / ((const float*)&sum4)[ti];
        *(float2*)&srow[ti * 512 + j0] = make_float2(eA[ti] * inv, eB[ti] * inv);
    }
    __syncthreads();

    // ---- PV: acc[ti][h=tid] = sum_j P[ti][j] * v[b][j][h] ----
    float accv[TI];
#pragma unroll
    for (int ti = 0; ti < TI; ++ti) accv[ti] = 0.f;
    {
        const float* vp = v + (size_t)b * NN * NH + tid;
        for (int j4 = 0; j4 < 128; ++j4) {
            const int j = 4 * j4;
            float v0 = vp[(size_t)(j + 0) * NH];
            float v1 = vp[(size_t)(j + 1) * NH];
            float v2 = vp[(size_t)(j + 2) * NH];
            float v3 = vp[(size_t)(j + 3) * NH];
#pragma unroll
            for (int ti = 0; ti < TI; ++ti) {
                float4 p4 = *(const float4*)&srow[ti * 512 + j];
                accv[ti] += p4.x * v0 + p4.y * v1 + p4.z * v2 + p4.w * v3;
            }
        }
    }

    // ---- LN1 -> y1 (reuse qs) ----
    float4 t4 = make_float4(accv[0], accv[1], accv[2], accv[3]);
    float4 mean4 = blockReduce4(t4, red4b, false);
    float dd[TI];
#pragma unroll
    for (int ti = 0; ti < TI; ++ti) {
        dd[ti] = accv[ti] - ((const float*)&mean4)[ti] * (1.f / 256.f);
        ((float*)&t4)[ti] = dd[ti] * dd[ti];
    }
    float4 var4 = blockReduce4(t4, red4b, false);
    const float g1v = g1[tid], b1v = b1[tid];
#pragma unroll
    for (int ti = 0; ti < TI; ++ti) {
        float y = dd[ti] * rsqrtf(((const float*)&var4)[ti] * (1.f / 256.f) + 1e-5f) * g1v + b1v;
        qs[ti * 256 + tid] = y;
    }
    __syncthreads();

    // ---- out2[ti][o=tid] = sum_h y1[ti][h] * Wo[o][h] + bo[o]  (Wo^T coalesced) ----
    float acc2[TI];
    const float bov = bo[tid];
#pragma unroll
    for (int ti = 0; ti < TI; ++ti) acc2[ti] = bov;
    for (int h4 = 0; h4 < 64; ++h4) {
        const int h = 4 * h4;
        float wv0 = Wot[(size_t)(h + 0) * 256 + tid];
        float wv1 = Wot[(size_t)(h + 1) * 256 + tid];
        float wv2 = Wot[(size_t)(h + 2) * 256 + tid];
        float wv3 = Wot[(size_t)(h + 3) * 256 + tid];
#pragma unroll
        for (int ti = 0; ti < TI; ++ti) {
            float4 y4 = *(const float4*)&qs[ti * 256 + h];
            acc2[ti] += y4.x * wv0 + y4.y * wv1 + y4.z * wv2 + y4.w * wv3;
        }
    }

    // ---- LN(g_ot,b_ot) + relu ----
#pragma unroll
    for (int ti = 0; ti < TI; ++ti) ((float*)&t4)[ti] = acc2[ti];
    mean4 = blockReduce4(t4, red4b, false);
#pragma unroll
    for (int ti = 0; ti < TI; ++ti) {
        dd[ti] = acc2[ti] - ((const float*)&mean4)[ti] * (1.f / 256.f);
        ((float*)&t4)[ti] = dd[ti] * dd[ti];
    }
    var4 = blockReduce4(t4, red4b, false);
    const float gotv = g_ot[tid], botv = b_ot[tid];
    float z[TI];
#pragma unroll
    for (int ti = 0; ti < TI; ++ti)
        z[ti] = fmaxf(dd[ti] * rsqrtf(((const float*)&var4)[ti] * (1.f / 256.f) + 1e-5f) * gotv + botv, 0.f);

    // ---- residual + LN2 ----
    float tt[TI];
#pragma unroll
    for (int ti = 0; ti < TI; ++ti) {
        tt[ti] = z[ti] + x[(size_t)(b * NN + i0 + ti) * ND + tid];
        ((float*)&t4)[ti] = tt[ti];
    }
    mean4 = blockReduce4(t4, red4b, false);
#pragma unroll
    for (int ti = 0; ti < TI; ++ti) {
        dd[ti] = tt[ti] - ((const float*)&mean4)[ti] * (1.f / 256.f);
        ((float*)&t4)[ti] = dd[ti] * dd[ti];
    }
    var4 = blockReduce4(t4, red4b, false);
    const float g2v = g2[tid], b2v = b2[tid];
#pragma unroll
    for (int ti = 0; ti < TI; ++ti) {
        float o = dd[ti] * rsqrtf(((const float*)&var4)[ti] * (1.f / 256.f) + 1e-5f) * g2v + b2v;
        out[(size_t)(b * NN + i0 + ti) * NH + tid] = o;
    }
}

extern "C" void kernel_launch(void* const* d_in, const int* in_sizes, int n_in,
                              void* d_out, int out_size, void* d_ws, size_t ws_size,
                              hipStream_t stream) {
    const float* x    = (const float*)d_in[0];
    const float* area = (const float*)d_in[1];
    const float* co   = (const float*)d_in[2];
    const float* Wq   = (const float*)d_in[3];
    const float* bq   = (const float*)d_in[4];
    const float* Wk   = (const float*)d_in[5];
    const float* bk   = (const float*)d_in[6];
    const float* Wv   = (const float*)d_in[7];
    const float* bv   = (const float*)d_in[8];
    const float* We1  = (const float*)d_in[9];
    const float* be1  = (const float*)d_in[10];
    const float* We2  = (const float*)d_in[11];
    const float* be2  = (const float*)d_in[12];
    const float* Wo   = (const float*)d_in[13];
    const float* bo   = (const float*)d_in[14];
    const float* g_ot = (const float*)d_in[15];
    const float* b_ot = (const float*)d_in[16];
    const float* g1   = (const float*)d_in[17];
    const float* b1   = (const float*)d_in[18];
    const float* g2   = (const float*)d_in[19];
    const float* b2   = (const float*)d_in[20];

    float* q   = (float*)d_ws;                       // 2 MB
    float* k_t = q + (size_t)NB * NN * NH;           // 2 MB
    float* v   = k_t + (size_t)NB * NN * NH;         // 2 MB
    float* Wqt = v + (size_t)NB * NN * NH;           // 256 KB each
    float* Wkt = Wqt + 256 * 256;
    float* Wvt = Wkt + 256 * 256;
    float* Wot = Wvt + 256 * 256;

    transpose_w<<<dim3(8, 8, 4), 256, 0, stream>>>(Wq, Wk, Wv, Wo, Wqt, Wkt, Wvt, Wot);
    qkv_proj<<<dim3(NB * NN / 16, 3), 256, 0, stream>>>(x, Wqt, bq, Wkt, bk, Wvt, bv, q, k_t, v);
    fused_kernel<<<NB * NN / TI, 256, 0, stream>>>(x, area, co, We1, be1, We2, be2, Wot, bo,
                                                   g_ot, b_ot, g1, b1, g2, b2, q, k_t, v,
                                                   (float*)d_out);
}

// Round 5
// 175.597 us; speedup vs baseline: 2.6723x; 1.2865x over previous
//
#include <hip/hip_runtime.h>

typedef unsigned short u16;
typedef unsigned int u32;

#define NB 4
#define NN 512
#define ND 256
#define NH 256
#define TI 4

typedef __attribute__((ext_vector_type(8))) short short8;
typedef __attribute__((ext_vector_type(4))) float f32x4;

__device__ __forceinline__ u16 f2bf(float f) {
    u32 t; __builtin_memcpy(&t, &f, 4);
    u32 r = (t + 0x7FFFu + ((t >> 16) & 1u)) >> 16;
    return (u16)r;
}

// ---- block-wide reduce of 4 independent values; 512 threads = 8 waves ----
__device__ __forceinline__ float4 blockReduce4(float4 v, float4* red4b, bool ismax) {
#pragma unroll
    for (int o = 32; o > 0; o >>= 1) {
        float4 t;
        t.x = __shfl_down(v.x, o); t.y = __shfl_down(v.y, o);
        t.z = __shfl_down(v.z, o); t.w = __shfl_down(v.w, o);
        if (ismax) {
            v.x = fmaxf(v.x, t.x); v.y = fmaxf(v.y, t.y);
            v.z = fmaxf(v.z, t.z); v.w = fmaxf(v.w, t.w);
        } else {
            v.x += t.x; v.y += t.y; v.z += t.z; v.w += t.w;
        }
    }
    int wid = threadIdx.x >> 6;
    __syncthreads();
    if ((threadIdx.x & 63) == 0) red4b[wid] = v;
    __syncthreads();
    float4 r = red4b[0];
#pragma unroll
    for (int w = 1; w < 8; ++w) {
        float4 u = red4b[w];
        if (ismax) {
            r.x = fmaxf(r.x, u.x); r.y = fmaxf(r.y, u.y);
            r.z = fmaxf(r.z, u.z); r.w = fmaxf(r.w, u.w);
        } else {
            r.x += u.x; r.y += u.y; r.z += u.z; r.w += u.w;
        }
    }
    return r;
}

// ---------------- K0a: fp32 -> bf16 convert for x and Wq/Wk/Wv ----------------
__global__ __launch_bounds__(256) void convert_k(
    const float* __restrict__ x, const float* __restrict__ Wq,
    const float* __restrict__ Wk, const float* __restrict__ Wv,
    u16* __restrict__ xb, u16* __restrict__ Wb)
{
    int t = blockIdx.x * 256 + threadIdx.x;   // grid covers 720896
    if (t < 524288) {
        xb[t] = f2bf(x[t]);
    } else {
        int u = t - 524288;                   // 0..196607
        const float* src = (u < 65536) ? Wq : (u < 131072) ? Wk : Wv;
        Wb[u] = f2bf(src[u & 65535]);
    }
}

// ---------------- K0b: transpose Wo (fp32) ----------------
__global__ __launch_bounds__(256) void transpose_wo(
    const float* __restrict__ Wo, float* __restrict__ Wot)
{
    __shared__ float t[32][33];
    const int tx = threadIdx.x & 31, ty = threadIdx.x >> 5;  // ty 0..7
#pragma unroll
    for (int k = 0; k < 4; ++k)
        t[ty + 8 * k][tx] = Wo[(blockIdx.y * 32 + ty + 8 * k) * 256 + blockIdx.x * 32 + tx];
    __syncthreads();
#pragma unroll
    for (int k = 0; k < 4; ++k)
        Wot[(blockIdx.x * 32 + ty + 8 * k) * 256 + blockIdx.y * 32 + tx] = t[tx][ty + 8 * k];
}

// ---------------- K1: q/k/v projections via bf16 MFMA ----------------
// grid (32 row-tiles of 64, 48 out-tiles of 16); 256 thr = 4 waves; wave owns 16x16 C.
// Wb rows: 0-255 = q, 256-511 = k, 512-767 = v. q,v row-major fp32; k -> k_t[b][h][n].
__global__ __launch_bounds__(256) void qkv_mfma(
    const u16* __restrict__ xb, const u16* __restrict__ Wb,
    const float* __restrict__ bq, const float* __restrict__ bk, const float* __restrict__ bv,
    float* __restrict__ q, float* __restrict__ k_t, float* __restrict__ v)
{
    const int lane = threadIdx.x & 63, wave = threadIdx.x >> 6;
    const int r0 = blockIdx.x * 64 + wave * 16;
    const int out0 = blockIdx.y * 16;
    const int which = blockIdx.y >> 4;
    const float* bia = (which == 0) ? bq : (which == 1) ? bk : bv;

    const int m = lane & 15, koff = (lane >> 4) * 8;
    const u16* Ap = xb + (size_t)(r0 + m) * 256 + koff;
    const u16* Bp = Wb + (size_t)(out0 + m) * 256 + koff;

    f32x4 acc = {0.f, 0.f, 0.f, 0.f};
#pragma unroll
    for (int kb = 0; kb < 8; ++kb) {
        short8 a  = *(const short8*)(Ap + kb * 32);
        short8 bf = *(const short8*)(Bp + kb * 32);
        acc = __builtin_amdgcn_mfma_f32_16x16x32_bf16(a, bf, acc, 0, 0, 0);
    }

    const int oc = (out0 + m) & 255;          // D col = lane&15
    const float bias = bia[oc];
    const int rbase = r0 + (lane >> 4) * 4;   // D row = (lane>>4)*4 + reg
#pragma unroll
    for (int reg = 0; reg < 4; ++reg) {
        int R = rbase + reg;
        float val = acc[reg] + bias;
        if (which == 1)      k_t[((size_t)(R >> 9) * 256 + oc) * 512 + (R & 511)] = val;
        else if (which == 0) q[(size_t)R * 256 + oc] = val;
        else                 v[(size_t)R * 256 + oc] = val;
    }
}

// ---------------- K2: fused attention, TI=4 rows, 512 threads ----------------
__global__ __launch_bounds__(512) void fused_kernel(
    const float* __restrict__ x, const float* __restrict__ area, const float* __restrict__ co,
    const float* __restrict__ We1, const float* __restrict__ be1,
    const float* __restrict__ We2, const float* __restrict__ be2,
    const float* __restrict__ Wot, const float* __restrict__ bo,
    const float* __restrict__ g_ot, const float* __restrict__ b_ot,
    const float* __restrict__ g1, const float* __restrict__ b1,
    const float* __restrict__ g2, const float* __restrict__ b2,
    const float* __restrict__ q, const float* __restrict__ k_t, const float* __restrict__ v,
    float* __restrict__ out)
{
    const int tid = threadIdx.x;
    const int b = blockIdx.x >> 7;
    const int i0 = (blockIdx.x & 127) << 2;

    __shared__ float ts[TI * 256];    // breakpoints; later: PV/Wo partial-combine buffer
    __shared__ float ea[TI * 256];    // slope deltas (scanned)
    __shared__ float eb[TI * 256];    // intercept deltas (scanned)
    __shared__ float srow[TI * 512];  // probs; later: y1 (first 1024 slots)
    __shared__ float4 red4b[8];

    const float be2f = be2[0];

    // ---- gate build (lower 256 threads; h = tid) ----
    float4 bS4 = make_float4(0, 0, 0, 0), bB4 = make_float4(0, 0, 0, 0);
    if (tid < 256) {
        const float w10 = We1[2 * tid], w11 = We1[2 * tid + 1];
        const float w2v = We2[tid], be1v = be1[tid];
#pragma unroll
        for (int ti = 0; ti < TI; ++ti) {
            const float a = area[b * NN + i0 + ti];
            float al = fmaf(a, w10, be1v);
            float s = w11 * w2v, bb = al * w2v;
            float t = 3e38f, es = 0.f, ebv = 0.f, baS = 0.f, baB = 0.f;
            if (w11 == 0.f) {
                if (al > 0.f) baB = bb;
            } else {
                float tt = -al / w11;
                if (w11 > 0.f) {
                    if (tt <= 0.f)      { baS = s; baB = bb; }
                    else if (tt < 1.f)  { t = tt; es = s; ebv = bb; }
                } else {
                    if (tt >= 1.f)      { baS = s; baB = bb; }
                    else if (tt > 0.f)  { t = tt; es = -s; ebv = -bb; baS = s; baB = bb; }
                }
            }
            ts[ti * 256 + tid] = t; ea[ti * 256 + tid] = es; eb[ti * 256 + tid] = ebv;
            ((float*)&bS4)[ti] = baS; ((float*)&bB4)[ti] = baB;
        }
    }
    const float4 baseS4 = blockReduce4(bS4, red4b, false);
    const float4 baseB4 = blockReduce4(bB4, red4b, false);

    // ---- bitonic sort, 4 sets x 128 pairs = 512 compares/stage ----
    {
        const int tiS = tid >> 7, pidS = tid & 127;
        for (int k2 = 2; k2 <= 256; k2 <<= 1) {
            for (int jj = k2 >> 1; jj > 0; jj >>= 1) {
                __syncthreads();
                int low = pidS & (jj - 1);
                int t = ((pidS - low) << 1) + low;
                int p = t + jj;
                bool up = ((t & k2) == 0);
                int a0 = tiS * 256 + t, a1 = tiS * 256 + p;
                float t0 = ts[a0], t1 = ts[a1];
                if ((t0 > t1) == up) {
                    ts[a0] = t1; ts[a1] = t0;
                    float u = ea[a0]; ea[a0] = ea[a1]; ea[a1] = u;
                    u = eb[a0]; eb[a0] = eb[a1]; eb[a1] = u;
                }
            }
        }
        __syncthreads();
    }

    // ---- inclusive scan of (ea, eb): 512 threads handle 2 (ti,col) items each ----
    {
        const int colS = tid & 255, tiA = (tid >> 8) * 2;
        for (int off = 1; off < 256; off <<= 1) {
            float va0 = ea[tiA * 256 + colS],       vb0 = eb[tiA * 256 + colS];
            float va1 = ea[(tiA + 1) * 256 + colS], vb1 = eb[(tiA + 1) * 256 + colS];
            if (colS >= off) {
                va0 += ea[tiA * 256 + colS - off];       vb0 += eb[tiA * 256 + colS - off];
                va1 += ea[(tiA + 1) * 256 + colS - off]; vb1 += eb[(tiA + 1) * 256 + colS - off];
            }
            __syncthreads();
            ea[tiA * 256 + colS] = va0;       eb[tiA * 256 + colS] = vb0;
            ea[(tiA + 1) * 256 + colS] = va1; eb[(tiA + 1) * 256 + colS] = vb1;
            __syncthreads();
        }
    }

    // ---- scores: j = tid; q rows via wave-uniform loads ----
    float sA[TI];
    {
        const int j = tid;
        float dot[TI] = {0.f, 0.f, 0.f, 0.f};
        const float* kt = k_t + (size_t)b * NH * NN;
        const float* qb_ = q + (size_t)(b * NN + i0) * NH;
        for (int h = 0; h < 256; h += 4) {
            float k0 = kt[(size_t)(h + 0) * 512 + j];
            float k1 = kt[(size_t)(h + 1) * 512 + j];
            float k2c = kt[(size_t)(h + 2) * 512 + j];
            float k3 = kt[(size_t)(h + 3) * 512 + j];
#pragma unroll
            for (int ti = 0; ti < TI; ++ti) {
                float4 qv = *(const float4*)&qb_[ti * 256 + h];  // wave-uniform
                dot[ti] += qv.x * k0 + qv.y * k1 + qv.z * k2c + qv.w * k3;
            }
        }
#pragma unroll
        for (int ti = 0; ti < TI; ++ti) {
            float c = co[(size_t)(i0 + ti) * NN + j];
            int r = 0;
#pragma unroll
            for (int st = 128; st; st >>= 1)
                if (ts[ti * 256 + r + st - 1] <= c) r += st;
            float S = ((const float*)&baseS4)[ti] + (r ? ea[ti * 256 + r - 1] : 0.f);
            float B = ((const float*)&baseB4)[ti] + (r ? eb[ti * 256 + r - 1] : 0.f);
            float e = fmaf(c, S, B);
            float ew = 1.f / (1.f + __expf(-(e + be2f)));
            sA[ti] = dot[ti] * 0.0625f * ew;
        }
    }

    // ---- softmax over j = 512 threads ----
    {
        float4 m4 = make_float4(sA[0], sA[1], sA[2], sA[3]);
        m4 = blockReduce4(m4, red4b, true);
        float eA[TI];
        float4 sum4;
#pragma unroll
        for (int ti = 0; ti < TI; ++ti) {
            eA[ti] = __expf(sA[ti] - ((const float*)&m4)[ti]);
            ((float*)&sum4)[ti] = eA[ti];
        }
        sum4 = blockReduce4(sum4, red4b, false);
#pragma unroll
        for (int ti = 0; ti < TI; ++ti)
            srow[ti * 512 + tid] = eA[ti] / ((const float*)&sum4)[ti];
        __syncthreads();
    }

    // ---- PV: h = tid&255, j-half = tid>>8 ----
    const int hP = tid & 255, half = tid >> 8;
    float accv[TI] = {0.f, 0.f, 0.f, 0.f};
    {
        const float* vp = v + (size_t)b * NN * NH + hP;
        for (int j4 = half * 64; j4 < half * 64 + 64; ++j4) {
            const int jj = 4 * j4;
            float v0 = vp[(size_t)(jj + 0) * NH];
            float v1 = vp[(size_t)(jj + 1) * NH];
            float v2 = vp[(size_t)(jj + 2) * NH];
            float v3 = vp[(size_t)(jj + 3) * NH];
#pragma unroll
            for (int ti = 0; ti < TI; ++ti) {
                float4 p4 = *(const float4*)&srow[ti * 512 + jj];
                accv[ti] += p4.x * v0 + p4.y * v1 + p4.z * v2 + p4.w * v3;
            }
        }
    }
    __syncthreads();
    if (half == 1) {
#pragma unroll
        for (int ti = 0; ti < TI; ++ti) ts[ti * 256 + hP] = accv[ti];
    }
    __syncthreads();
    if (half == 0) {
#pragma unroll
        for (int ti = 0; ti < TI; ++ti) accv[ti] += ts[ti * 256 + hP];
    }

    // ---- LN1 -> y1 (stored in srow[0..1023]) ----
    float4 t4;
    float dd[TI];
#pragma unroll
    for (int ti = 0; ti < TI; ++ti) ((float*)&t4)[ti] = (half == 0) ? accv[ti] : 0.f;
    float4 mean4 = blockReduce4(t4, red4b, false);
#pragma unroll
    for (int ti = 0; ti < TI; ++ti) {
        dd[ti] = (half == 0) ? accv[ti] - ((const float*)&mean4)[ti] * (1.f / 256.f) : 0.f;
        ((float*)&t4)[ti] = dd[ti] * dd[ti];
    }
    float4 var4 = blockReduce4(t4, red4b, false);
    if (half == 0) {
        const float g1v = g1[hP], b1v = b1[hP];
#pragma unroll
        for (int ti = 0; ti < TI; ++ti)
            srow[ti * 256 + hP] = dd[ti] * rsqrtf(((const float*)&var4)[ti] * (1.f / 256.f) + 1e-5f) * g1v + b1v;
    }
    __syncthreads();

    // ---- Wo GEMV: o = tid&255, d-half = tid>>8 (Wot coalesced, y1 via LDS) ----
    float acc2[TI] = {0.f, 0.f, 0.f, 0.f};
    {
        for (int d4 = half * 32; d4 < half * 32 + 32; ++d4) {
            const int d = 4 * d4;
            float w0 = Wot[(size_t)(d + 0) * 256 + hP];
            float w1 = Wot[(size_t)(d + 1) * 256 + hP];
            float w2c = Wot[(size_t)(d + 2) * 256 + hP];
            float w3 = Wot[(size_t)(d + 3) * 256 + hP];
#pragma unroll
            for (int ti = 0; ti < TI; ++ti) {
                float4 y4 = *(const float4*)&srow[ti * 256 + d];
                acc2[ti] += y4.x * w0 + y4.y * w1 + y4.z * w2c + y4.w * w3;
            }
        }
    }
    __syncthreads();
    if (half == 1) {
#pragma unroll
        for (int ti = 0; ti < TI; ++ti) ts[ti * 256 + hP] = acc2[ti];
    }
    __syncthreads();
    if (half == 0) {
        const float bov = bo[hP];
#pragma unroll
        for (int ti = 0; ti < TI; ++ti) acc2[ti] += ts[ti * 256 + hP] + bov;
    }

    // ---- LN(g_ot, b_ot) + relu ----
#pragma unroll
    for (int ti = 0; ti < TI; ++ti) ((float*)&t4)[ti] = (half == 0) ? acc2[ti] : 0.f;
    mean4 = blockReduce4(t4, red4b, false);
#pragma unroll
    for (int ti = 0; ti < TI; ++ti) {
        dd[ti] = (half == 0) ? acc2[ti] - ((const float*)&mean4)[ti] * (1.f / 256.f) : 0.f;
        ((float*)&t4)[ti] = dd[ti] * dd[ti];
    }
    var4 = blockReduce4(t4, red4b, false);
    float z[TI];
    const float gotv = (half == 0) ? g_ot[hP] : 0.f;
    const float botv = (half == 0) ? b_ot[hP] : 0.f;
#pragma unroll
    for (int ti = 0; ti < TI; ++ti)
        z[ti] = fmaxf(dd[ti] * rsqrtf(((const float*)&var4)[ti] * (1.f / 256.f) + 1e-5f) * gotv + botv, 0.f);

    // ---- residual + LN2 ----
    float tt[TI];
#pragma unroll
    for (int ti = 0; ti < TI; ++ti) {
        tt[ti] = (half == 0) ? z[ti] + x[(size_t)(b * NN + i0 + ti) * ND + hP] : 0.f;
        ((float*)&t4)[ti] = tt[ti];
    }
    mean4 = blockReduce4(t4, red4b, false);
#pragma unroll
    for (int ti = 0; ti < TI; ++ti) {
        dd[ti] = (half == 0) ? tt[ti] - ((const float*)&mean4)[ti] * (1.f / 256.f) : 0.f;
        ((float*)&t4)[ti] = dd[ti] * dd[ti];
    }
    var4 = blockReduce4(t4, red4b, false);
    if (half == 0) {
        const float g2v = g2[hP], b2v = b2[hP];
#pragma unroll
        for (int ti = 0; ti < TI; ++ti) {
            float o = dd[ti] * rsqrtf(((const float*)&var4)[ti] * (1.f / 256.f) + 1e-5f) * g2v + b2v;
            out[(size_t)(b * NN + i0 + ti) * NH + hP] = o;
        }
    }
}

extern "C" void kernel_launch(void* const* d_in, const int* in_sizes, int n_in,
                              void* d_out, int out_size, void* d_ws, size_t ws_size,
                              hipStream_t stream) {
    const float* x    = (const float*)d_in[0];
    const float* area = (const float*)d_in[1];
    const float* co   = (const float*)d_in[2];
    const float* Wq   = (const float*)d_in[3];
    const float* bq   = (const float*)d_in[4];
    const float* Wk   = (const float*)d_in[5];
    const float* bk   = (const float*)d_in[6];
    const float* Wv   = (const float*)d_in[7];
    const float* bv   = (const float*)d_in[8];
    const float* We1  = (const float*)d_in[9];
    const float* be1  = (const float*)d_in[10];
    const float* We2  = (const float*)d_in[11];
    const float* be2  = (const float*)d_in[12];
    const float* Wo   = (const float*)d_in[13];
    const float* bo   = (const float*)d_in[14];
    const float* g_ot = (const float*)d_in[15];
    const float* b_ot = (const float*)d_in[16];
    const float* g1   = (const float*)d_in[17];
    const float* b1   = (const float*)d_in[18];
    const float* g2   = (const float*)d_in[19];
    const float* b2   = (const float*)d_in[20];

    float* q   = (float*)d_ws;                         // 2 MB
    float* k_t = q + (size_t)NB * NN * NH;             // 2 MB
    float* v   = k_t + (size_t)NB * NN * NH;           // 2 MB
    float* Wot = v + (size_t)NB * NN * NH;             // 256 KB
    u16*   xb  = (u16*)(Wot + 256 * 256);              // 1 MB
    u16*   Wb  = xb + (size_t)NB * NN * ND;            // 384 KB

    convert_k<<<2816, 256, 0, stream>>>(x, Wq, Wk, Wv, xb, Wb);
    transpose_wo<<<dim3(8, 8), 256, 0, stream>>>(Wo, Wot);
    qkv_mfma<<<dim3(32, 48), 256, 0, stream>>>(xb, Wb, bq, bk, bv, q, k_t, v);
    fused_kernel<<<NB * NN / TI, 512, 0, stream>>>(x, area, co, We1, be1, We2, be2, Wot, bo,
                                                   g_ot, b_ot, g1, b1, g2, b2, q, k_t, v,
                                                   (float*)d_out);
}